// Round 4
// baseline (1271.858 us; speedup 1.0000x reference)
//
#include <hip/hip_runtime.h>

#define HD 64  // hidden dim

// ---------------------------------------------------------------------------
// zero-fill ints
// ---------------------------------------------------------------------------
__global__ void __launch_bounds__(256) zero_int_kernel(int* p, long n) {
    long i = blockIdx.x * (long)blockDim.x + threadIdx.x;
    long stride = (long)gridDim.x * blockDim.x;
    for (; i < n; i += stride) p[i] = 0;
}

// ---------------------------------------------------------------------------
// histogram of dst into cnt
// ---------------------------------------------------------------------------
__global__ void __launch_bounds__(256) hist_kernel(const int* __restrict__ dst,
                                                   int* __restrict__ cnt, long E) {
    long i = blockIdx.x * (long)blockDim.x + threadIdx.x;
    long stride = (long)gridDim.x * blockDim.x;
    for (; i < E; i += stride) atomicAdd(&cnt[dst[i]], 1);
}

// ---------------------------------------------------------------------------
// scan stage 1: per-256-chunk sums
// ---------------------------------------------------------------------------
__global__ void __launch_bounds__(256) blocksum_kernel(const int* __restrict__ cnt,
                                                       int* __restrict__ bsum, int N) {
    int i = blockIdx.x * 256 + threadIdx.x;
    int v = (i < N) ? cnt[i] : 0;
    #pragma unroll
    for (int off = 32; off; off >>= 1) v += __shfl_down(v, off, 64);
    __shared__ int s[4];
    if ((threadIdx.x & 63) == 0) s[threadIdx.x >> 6] = v;
    __syncthreads();
    if (threadIdx.x == 0) bsum[blockIdx.x] = s[0] + s[1] + s[2] + s[3];
}

// ---------------------------------------------------------------------------
// scan stage 2: single block scans the (<=512) chunk sums -> exclusive bpre
// ---------------------------------------------------------------------------
__global__ void __launch_bounds__(512) scan2_kernel(const int* __restrict__ bsum,
                                                    int* __restrict__ bpre,
                                                    int* __restrict__ offs,
                                                    int nb, int N, int E) {
    __shared__ int s[512];
    int tid = threadIdx.x;
    int v = (tid < nb) ? bsum[tid] : 0;
    s[tid] = v;
    __syncthreads();
    for (int off = 1; off < 512; off <<= 1) {
        int add = (tid >= off) ? s[tid - off] : 0;
        __syncthreads();
        s[tid] += add;
        __syncthreads();
    }
    if (tid < nb) bpre[tid] = s[tid] - v;  // exclusive
    if (tid == 0) offs[N] = E;
}

// ---------------------------------------------------------------------------
// scan stage 3: per-chunk exclusive scan + chunk prefix -> offs, cursor
// ---------------------------------------------------------------------------
__global__ void __launch_bounds__(256) scan3_kernel(const int* __restrict__ cnt,
                                                    const int* __restrict__ bpre,
                                                    int* __restrict__ offs,
                                                    int* __restrict__ cursor, int N) {
    __shared__ int s[256];
    int tid = threadIdx.x;
    int i = blockIdx.x * 256 + tid;
    int v = (i < N) ? cnt[i] : 0;
    s[tid] = v;
    __syncthreads();
    for (int off = 1; off < 256; off <<= 1) {
        int add = (tid >= off) ? s[tid - off] : 0;
        __syncthreads();
        s[tid] += add;
        __syncthreads();
    }
    if (i < N) {
        int excl = s[tid] - v + bpre[blockIdx.x];
        offs[i] = excl;
        cursor[i] = excl;
    }
}

// ---------------------------------------------------------------------------
// fill permutation: for each edge, place {edge_id, src} as int2 into CSR slot
// (single 8B scattered store instead of two 4B stores to separate arrays)
// ---------------------------------------------------------------------------
__global__ void __launch_bounds__(256) fill_kernel(const int* __restrict__ src,
                                                   const int* __restrict__ dst,
                                                   int* __restrict__ cursor,
                                                   int2* __restrict__ ps, long E) {
    long i = blockIdx.x * (long)blockDim.x + threadIdx.x;
    long stride = (long)gridDim.x * blockDim.x;
    for (; i < E; i += stride) {
        int d = dst[i];
        int p = atomicAdd(&cursor[d], 1);
        ps[p] = make_int2((int)i, src[i]);
    }
}

// ---------------------------------------------------------------------------
// node init: h = relu([emb[z], t] @ rw1 + rb1) @ rw2 + rb2
// (exact round-0 verified version: one node per wave, per-wave LDS slices)
// ---------------------------------------------------------------------------
__global__ void __launch_bounds__(512, 6) node_init_kernel(
    const int* __restrict__ z, const float* __restrict__ t,
    const float* __restrict__ emb,
    const float* __restrict__ rw1, const float* __restrict__ rb1,
    const float* __restrict__ rw2, const float* __restrict__ rb2,
    float* __restrict__ h, int N)
{
    __shared__ float s_w1[65 * 64];
    __shared__ float s_w2[64 * 64];
    __shared__ float s_x[8][66];
    __shared__ float s_y1[8][64];

    int tid = threadIdx.x;
    for (int i = tid; i < 65 * 64; i += 512) s_w1[i] = rw1[i];
    for (int i = tid; i < 64 * 64; i += 512) s_w2[i] = rw2[i];
    __syncthreads();

    int wv = tid >> 6;   // 0..7
    int c  = tid & 63;
    float b1 = rb1[c];
    float b2 = rb2[c];

    long stride = (long)gridDim.x * 8;
    for (long base = (long)blockIdx.x * 8; base < N; base += stride) {
        long node = base + wv;
        if (node >= N) continue;
        s_x[wv][c] = emb[(long)z[node] * HD + c];
        if (c == 0) s_x[wv][64] = t[node];
        float acc = b1;
        #pragma unroll
        for (int k = 0; k < 65; ++k)
            acc = fmaf(s_x[wv][k], s_w1[k * 64 + c], acc);
        s_y1[wv][c] = fmaxf(acc, 0.f);
        float acc2 = b2;
        #pragma unroll
        for (int k = 0; k < 64; ++k)
            acc2 = fmaf(s_y1[wv][k], s_w2[k * 64 + c], acc2);
        h[node * HD + c] = acc2;
    }
}

// ---------------------------------------------------------------------------
// gather kernel: agg[n] = h[n] + sum_{edges into n} relu(h[src] + ea[e])
// One node per wave, NO LDS, launch_bounds(256,8) => <=64 VGPR, 32 waves/CU.
// Edge loop in batches of 16: 4 int2 index loads + 8 dwordx4 data loads all
// issued before one vmcnt wait (2 latency exposures per 16 edges). Slots past
// the end are clamped to a valid slot and masked out via fma multiplier.
// ---------------------------------------------------------------------------
__global__ void __launch_bounds__(256, 8) gather_kernel(
    const int* __restrict__ offs, const int2* __restrict__ ps,
    const float* __restrict__ h, const float* __restrict__ ea,
    float* __restrict__ agg, int N)
{
    int tid  = threadIdx.x;
    int wv   = tid >> 6;        // 0..3
    int lane = tid & 63;
    int eg   = lane >> 4;       // edge group 0..3
    int cq   = (lane & 15) * 4; // channel-quad base

    long nw = (long)gridDim.x * 4;
    for (long node = (long)blockIdx.x * 4 + wv; node < N; node += nw) {
        int jb = offs[node], je = offs[node + 1];
        float4 acc; acc.x = acc.y = acc.z = acc.w = 0.f;

        for (int j0 = jb + eg; j0 < je; j0 += 16) {
            int2  pp[4];
            float m[4];
            #pragma unroll
            for (int u = 0; u < 4; ++u) {
                int jj = j0 + u * 4;
                bool v = jj < je;
                m[u]  = v ? 1.f : 0.f;
                pp[u] = ps[v ? jj : jb];
            }
            float4 av[4], hv[4];
            #pragma unroll
            for (int u = 0; u < 4; ++u) {
                av[u] = *(const float4*)(ea + (long)pp[u].x * HD + cq);
                hv[u] = *(const float4*)(h  + (long)pp[u].y * HD + cq);
            }
            #pragma unroll
            for (int u = 0; u < 4; ++u) {
                acc.x = fmaf(m[u], fmaxf(av[u].x + hv[u].x, 0.f), acc.x);
                acc.y = fmaf(m[u], fmaxf(av[u].y + hv[u].y, 0.f), acc.y);
                acc.z = fmaf(m[u], fmaxf(av[u].z + hv[u].z, 0.f), acc.z);
                acc.w = fmaf(m[u], fmaxf(av[u].w + hv[u].w, 0.f), acc.w);
            }
        }
        // reduce the 4 edge groups (lanes l, l^16, l^32, l^48 share cq)
        #pragma unroll
        for (int mm = 16; mm <= 32; mm <<= 1) {
            acc.x += __shfl_xor(acc.x, mm, 64);
            acc.y += __shfl_xor(acc.y, mm, 64);
            acc.z += __shfl_xor(acc.z, mm, 64);
            acc.w += __shfl_xor(acc.w, mm, 64);
        }
        if (lane < 16) {
            const float4 hh = *(const float4*)(h + node * HD + cq);
            acc.x += hh.x; acc.y += hh.y; acc.z += hh.z; acc.w += hh.w;
            *(float4*)(agg + node * HD + cq) = acc;
        }
    }
}

// ---------------------------------------------------------------------------
// MLP kernel: out[n] = (mlp(x[n]) [+relu]) + hres[n], 8 nodes per wave.
// Weights transposed+swizzled in LDS (verified R3 layout), read as b128:
// each weight read feeds 8 independent fma chains -> weight LDS bytes /8.
// x rows staged per-wave in LDS, read as wave-uniform float4 broadcasts.
// In-place safe (x rows fully consumed into LDS before out rows written).
// N assumed divisible by 8 (100000 = 12500*8).
// ---------------------------------------------------------------------------
__global__ void __launch_bounds__(512, 6) mlp_kernel(
    const float* __restrict__ x, const float* __restrict__ hres,
    const float* __restrict__ w1, const float* __restrict__ b1,
    const float* __restrict__ w2, const float* __restrict__ b2,
    float* __restrict__ out, int N, int relu_flag)
{
    __shared__ float s_w1[64 * 64];   // transposed+swizzled
    __shared__ float s_w2[64 * 64];   // transposed+swizzled
    __shared__ float s_x[8][512];     // per-wave 8 rows of 64

    int tid = threadIdx.x;
    for (int i = tid; i < 64 * 64; i += 512) {
        int k = i >> 6, cc = i & 63;
        int q = k >> 2, r = k & 3;
        int idx = (cc << 6) + ((q ^ (cc & 7)) << 2) + r;
        s_w1[idx] = w1[i];
        s_w2[idx] = w2[i];
    }
    __syncthreads();

    int wv = tid >> 6;    // 0..7
    int c  = tid & 63;
    float* sx = s_x[wv];
    int wbase = c << 6;
    int wsel  = (c & 7) << 2;
    float bb1 = b1[c];
    float bb2 = b2[c];

    long ngroups = (long)(N + 7) >> 3;
    long gstride = (long)gridDim.x * 8;
    for (long g = (long)blockIdx.x * 8 + wv; g < ngroups; g += gstride) {
        long base = g << 3;   // first node of this 8-node group

        // stage 8 rows (2KB) coalesced: lane covers flat [c*8, c*8+8)
        {
            const float4 v0 = *(const float4*)(x + base * HD + (c << 3));
            const float4 v1 = *(const float4*)(x + base * HD + (c << 3) + 4);
            *(float4*)&sx[(c << 3)]     = v0;
            *(float4*)&sx[(c << 3) + 4] = v1;
        }
        // prefetch residuals
        float hr[8];
        #pragma unroll
        for (int n = 0; n < 8; ++n) hr[n] = hres[(base + n) * HD + c];

        float acc[8];
        #pragma unroll
        for (int n = 0; n < 8; ++n) acc[n] = bb1;
        #pragma unroll
        for (int q = 0; q < 16; ++q) {
            const float4 wq = *(const float4*)&s_w1[wbase + ((q << 2) ^ wsel)];
            #pragma unroll
            for (int n = 0; n < 8; ++n) {
                const float4 xq = *(const float4*)&sx[(n << 6) + (q << 2)];
                acc[n] = fmaf(xq.x, wq.x, acc[n]);
                acc[n] = fmaf(xq.y, wq.y, acc[n]);
                acc[n] = fmaf(xq.z, wq.z, acc[n]);
                acc[n] = fmaf(xq.w, wq.w, acc[n]);
            }
        }
        // y1 rows overwrite x rows (x fully consumed); in-wave lgkmcnt orders
        #pragma unroll
        for (int n = 0; n < 8; ++n) sx[(n << 6) + c] = fmaxf(acc[n], 0.f);

        #pragma unroll
        for (int n = 0; n < 8; ++n) acc[n] = bb2;
        #pragma unroll
        for (int q = 0; q < 16; ++q) {
            const float4 wq = *(const float4*)&s_w2[wbase + ((q << 2) ^ wsel)];
            #pragma unroll
            for (int n = 0; n < 8; ++n) {
                const float4 xq = *(const float4*)&sx[(n << 6) + (q << 2)];
                acc[n] = fmaf(xq.x, wq.x, acc[n]);
                acc[n] = fmaf(xq.y, wq.y, acc[n]);
                acc[n] = fmaf(xq.z, wq.z, acc[n]);
                acc[n] = fmaf(xq.w, wq.w, acc[n]);
            }
        }
        #pragma unroll
        for (int n = 0; n < 8; ++n) {
            float v = acc[n];
            if (relu_flag) v = fmaxf(v, 0.f);
            out[(base + n) * HD + c] = v + hr[n];
        }
    }
}

// ---------------------------------------------------------------------------
extern "C" void kernel_launch(void* const* d_in, const int* in_sizes, int n_in,
                              void* d_out, int out_size, void* d_ws, size_t ws_size,
                              hipStream_t stream)
{
    const int*   z    = (const int*)  d_in[0];
    const int*   ei   = (const int*)  d_in[1];
    const float* ea   = (const float*)d_in[2];
    const float* t    = (const float*)d_in[3];
    const float* emb  = (const float*)d_in[4];
    const float* rw1  = (const float*)d_in[5];
    const float* rb1  = (const float*)d_in[6];
    const float* rw2  = (const float*)d_in[7];
    const float* rb2  = (const float*)d_in[8];
    const float* cw1  = (const float*)d_in[9];
    const float* cb1  = (const float*)d_in[10];
    const float* cw2  = (const float*)d_in[11];
    const float* cb2  = (const float*)d_in[12];

    int  N = in_sizes[0];
    long E = (long)in_sizes[1] / 2;
    const int* src = ei;        // edge_index[0]
    const int* dst = ei + E;    // edge_index[1]

    float* out = (float*)d_out;

    // workspace layout
    float* bufA   = (float*)d_ws;                 // N*HD floats
    int*   offs   = (int*)(bufA + (long)N * HD);  // N+1
    int*   cursor = offs + (N + 1);               // N
    int2*  ps     = (int2*)(cursor + N + 1);      // E int2 (8B aligned)
    int*   bsum   = (int*)(ps + E);               // nb
    int    nb     = (N + 255) / 256;
    int*   bpre   = bsum + nb;                    // nb

    // --- build CSR-by-dst index ---
    zero_int_kernel<<<256, 256, 0, stream>>>(cursor, N);
    hist_kernel<<<2048, 256, 0, stream>>>(dst, cursor, E);
    blocksum_kernel<<<nb, 256, 0, stream>>>(cursor, bsum, N);
    scan2_kernel<<<1, 512, 0, stream>>>(bsum, bpre, offs, nb, N, (int)E);
    scan3_kernel<<<nb, 256, 0, stream>>>(cursor, bpre, offs, cursor, N);
    fill_kernel<<<2048, 256, 0, stream>>>(src, dst, cursor, ps, E);

    // --- h0 = init MLP ---
    node_init_kernel<<<1024, 512, 0, stream>>>(z, t, emb, rw1, rb1, rw2, rb2,
                                               bufA, N);

    // --- 3 GINE layers: gather + mlp, ping-pong bufA <-> d_out ---
    float* hcur = bufA;
    for (int li = 0; li < 3; ++li) {
        float* hout = (li == 1) ? bufA : out;  // d_out, bufA, d_out
        gather_kernel<<<8192, 256, 0, stream>>>(offs, ps, hcur, ea, hout, N);
        mlp_kernel<<<1568, 512, 0, stream>>>(
            hout, hcur,
            cw1 + (long)li * HD * HD, cb1 + (long)li * HD,
            cw2 + (long)li * HD * HD, cb2 + (long)li * HD,
            hout, N, (li < 2) ? 1 : 0);
        hcur = hout;
    }
}